// Round 4
// baseline (528.502 us; speedup 1.0000x reference)
//
#include <hip/hip_runtime.h>

#define B_   2
#define S_   2048
#define E_   2048
#define QKV_ 3072
#define NH   16
#define NKV  4
#define HD   128

typedef __attribute__((ext_vector_type(8))) short bf16x8;
typedef __attribute__((ext_vector_type(4))) float f32x4;
typedef unsigned short u16;
typedef unsigned int   u32;

__device__ __forceinline__ float bf2f(u16 u) {
  union { u32 i; float f; } v; v.i = ((u32)u) << 16; return v.f;
}
__device__ __forceinline__ u16 f2bf(float f) {
  union { float f; u32 u; } v; v.f = f;
  return (u16)((v.u + 0x7FFFu + ((v.u >> 16) & 1u)) >> 16);
}
__device__ __forceinline__ void load_lds16(const u16* g, u16* l) {
  __builtin_amdgcn_global_load_lds((const __attribute__((address_space(1))) void*)g,
                                   (__attribute__((address_space(3))) void*)l, 16, 0, 0);
}

// ---------------- fp32 -> bf16 bulk convert (n multiple of 4) ----------------
__global__ __launch_bounds__(256) void f2b_conv(const float* __restrict__ in,
                                                u16* __restrict__ out, int n4) {
  const int i = blockIdx.x * 256 + threadIdx.x;
  if (i >= n4) return;
  const float4 v = ((const float4*)in)[i];
  ushort4 o;
  o.x = f2bf(v.x); o.y = f2bf(v.y); o.z = f2bf(v.z); o.w = f2bf(v.w);
  ((ushort4*)out)[i] = o;
}

// ---------------- rope table: cos/sin[s*64+i] ----------------
__global__ __launch_bounds__(256) void rope_tab(float* __restrict__ c,
                                                float* __restrict__ s) {
  const int idx = blockIdx.x * 256 + threadIdx.x;  // 2048*64
  const int t = idx >> 6, i = idx & 63;
  const float invf = powf(10000.0f, -(float)i * (1.0f / 64.0f));
  float sn, cs;
  sincosf((float)t * invf, &sn, &cs);
  c[idx] = cs; s[idx] = sn;
}

// ---------------- GEMM: C[M,N] = A[M,K] * B[N,K]^T + bias[N] ----------------
template <int OUT_BF16>
__global__ __launch_bounds__(256) void gemm_bt(const u16* __restrict__ A,
                                               const u16* __restrict__ Bm,
                                               const float* __restrict__ bias,
                                               void* __restrict__ C,
                                               int M, int N, int K) {
  __shared__ u16 As[128 * 32];
  __shared__ u16 Bs[128 * 32];
  const int tid = threadIdx.x;
  const int wave = tid >> 6, lane = tid & 63;
  const int m0 = blockIdx.y * 128, n0 = blockIdx.x * 128;
  const int wm = (wave & 1) * 64, wn = (wave >> 1) * 64;
  const int L15 = lane & 15, Lq = lane >> 4;
  const int lrow = lane >> 2, lcol = (lane & 3) * 8;

  f32x4 acc[4][4] = {};

  for (int k0 = 0; k0 < K; k0 += 32) {
#pragma unroll
    for (int c = 0; c < 2; ++c) {
      const int chunk = c * 4 + wave;
      const int row = chunk * 16 + lrow;
      load_lds16(A  + (size_t)(m0 + row) * K + k0 + lcol, &As[chunk * 512 + lane * 8]);
      load_lds16(Bm + (size_t)(n0 + row) * K + k0 + lcol, &Bs[chunk * 512 + lane * 8]);
    }
    __syncthreads();
    bf16x8 af[4], bfr[4];
#pragma unroll
    for (int t = 0; t < 4; ++t) {
      af[t]  = *(const bf16x8*)&As[(wm + t * 16 + L15) * 32 + Lq * 8];
      bfr[t] = *(const bf16x8*)&Bs[(wn + t * 16 + L15) * 32 + Lq * 8];
    }
#pragma unroll
    for (int mt = 0; mt < 4; ++mt)
#pragma unroll
      for (int nt = 0; nt < 4; ++nt)
        acc[mt][nt] = __builtin_amdgcn_mfma_f32_16x16x32_bf16(af[mt], bfr[nt], acc[mt][nt], 0, 0, 0);
    __syncthreads();
  }

#pragma unroll
  for (int nt = 0; nt < 4; ++nt) {
    const int col = n0 + wn + nt * 16 + L15;
    const float bv = bias[col];
#pragma unroll
    for (int mt = 0; mt < 4; ++mt) {
#pragma unroll
      for (int r = 0; r < 4; ++r) {
        const int row = m0 + wm + mt * 16 + Lq * 4 + r;
        const float v = acc[mt][nt][r] + bv;
        if (OUT_BF16) ((u16*)C)[(size_t)row * N + col] = f2bf(v);
        else          ((float*)C)[(size_t)row * N + col] = v;
      }
    }
  }
}

// ------------- depthwise causal conv(4) + bias + RoPE + split/layout -------------
// pair-vectorized: each unit handles 2 adjacent rotary lanes (u32 loads/stores)
__global__ __launch_bounds__(256) void conv_rope(const u16* __restrict__ qkv,
                                                 const float* __restrict__ cw,
                                                 const float* __restrict__ cb,
                                                 const float* __restrict__ ct,
                                                 const float* __restrict__ st,
                                                 u16* __restrict__ qo,
                                                 u16* __restrict__ ko,
                                                 u16* __restrict__ vo) {
  const int bs = blockIdx.x;
  const int b = bs >> 11, s = bs & 2047;
  const int tid = threadIdx.x;

  // conv of features f, f+1 (f even)
  auto conv2 = [&](int f, float& a0, float& a1) {
    a0 = cb[f]; a1 = cb[f + 1];
    const float4 w0 = *(const float4*)&cw[f * 4];
    const float4 w1 = *(const float4*)&cw[(f + 1) * 4];
    const float wa0[4] = {w0.x, w0.y, w0.z, w0.w};
    const float wa1[4] = {w1.x, w1.y, w1.z, w1.w};
#pragma unroll
    for (int d = 0; d < 4; ++d) {
      const int t = s - 3 + d;
      if (t >= 0) {
        const u32 pk = *(const u32*)&qkv[((size_t)b * S_ + t) * QKV_ + f];
        a0 += wa0[d] * bf2f((u16)pk);
        a1 += wa1[d] * bf2f((u16)(pk >> 16));
      }
    }
  };

  // rotary pair-units: (NH+NKV)*32 = 640
  for (int p = tid; p < (NH + NKV) * 32; p += 256) {
    int f1, i; u16* outp; float scale;
    if (p < NH * 32) {
      const int h = p >> 5; i = (p & 31) * 2;
      f1 = h * HD + i;
      outp = qo + ((size_t)(b * NH + h) * S_ + s) * HD;
      scale = 0.08838834764831845f;  // 1/sqrt(128)
    } else {
      const int pk = p - NH * 32;
      const int h = pk >> 5; i = (pk & 31) * 2;
      f1 = NH * HD + h * HD + i;
      outp = ko + ((size_t)(b * NKV + h) * S_ + s) * HD;
      scale = 1.0f;
    }
    float x1a, x1b, x2a, x2b;
    conv2(f1, x1a, x1b);
    conv2(f1 + 64, x2a, x2b);
    const float2 cs = *(const float2*)&ct[s * 64 + i];
    const float2 sn = *(const float2*)&st[s * 64 + i];
    u32 lo = (u32)f2bf((x1a * cs.x - x2a * sn.x) * scale) |
             ((u32)f2bf((x1b * cs.y - x2b * sn.y) * scale) << 16);
    u32 hi = (u32)f2bf((x2a * cs.x + x1a * sn.x) * scale) |
             ((u32)f2bf((x2b * cs.y + x1b * sn.y) * scale) << 16);
    *(u32*)&outp[i] = lo;
    *(u32*)&outp[i + 64] = hi;
  }
  // v: 256 pair-units, stored transposed (d-major)
  {
    const int p = tid;
    const int h = p >> 6, d = (p & 63) * 2;
    const int f = (NH + NKV) * HD + h * HD + d;
    float v0, v1;
    conv2(f, v0, v1);
    u16* vp = vo + ((size_t)(b * NKV + h) * HD + d) * S_ + s;
    vp[0]  = f2bf(v0);
    vp[S_] = f2bf(v1);
  }
}

// ------------------------- flash attention (causal, GQA) -------------------------
// grid (16, B*NH); block q-tile 128 rows, 4 waves x 32 rows.
// K-tile 64x128 / V^T-tile 128x64 staged by global_load_lds with XOR chunk
// swizzle: LDS slot (row, cp) holds global chunk cp^(row&7) -> conflict-free
// ds_read_b128 on both staging-write and frag-read sides.
#define PST 72  // P row stride (u16): 144B = 9*16B aligned, 36 dw = 4 mod 32
__global__ __launch_bounds__(256, 3) void attn(const u16* __restrict__ q,
                                               const u16* __restrict__ k,
                                               const u16* __restrict__ v,
                                               u16* __restrict__ ctx) {
  __shared__ u16 Ks[64 * 128];
  __shared__ u16 Vs[128 * 64];
  __shared__ u16 P[4][32 * PST];
  const int tid = threadIdx.x, wave = tid >> 6, lane = tid & 63;
  const int L15 = lane & 15, Lq = lane >> 4;
  const int qt = gridDim.x - 1 - blockIdx.x;  // longest blocks first
  const int bh = blockIdx.y;
  const int b = bh >> 4, h = bh & 15, hk = h >> 2;
  const int q0 = qt * 128;
  const int base = q0 + wave * 32;  // this wave's first q row

  bf16x8 qf[2][4];
#pragma unroll
  for (int rt = 0; rt < 2; ++rt) {
    const u16* qp = q + ((size_t)bh * S_ + base + rt * 16 + L15) * HD + Lq * 8;
#pragma unroll
    for (int c = 0; c < 4; ++c) qf[rt][c] = *(const bf16x8*)(qp + c * 32);
  }

  const int rx = L15 & 7;
  int koff[4], voff[2];
#pragma unroll
  for (int c = 0; c < 4; ++c) koff[c] = ((c * 4 + Lq) ^ rx) * 8;
#pragma unroll
  for (int kc = 0; kc < 2; ++kc) voff[kc] = ((kc * 4 + Lq) ^ rx) * 8;

  f32x4 acc[2][8] = {};
  float m_i[2][4], l_i[2][4];
#pragma unroll
  for (int rt = 0; rt < 2; ++rt)
#pragma unroll
    for (int r = 0; r < 4; ++r) { m_i[rt][r] = -1e30f; l_i[rt][r] = 0.f; }

  const u16* kb = k + (size_t)(b * NKV + hk) * S_ * HD;
  const u16* vb = v + (size_t)(b * NKV + hk) * HD * S_;

  const int ktmax = 2 * (qt + 1);
  for (int kt = 0; kt < ktmax; ++kt) {
    const int k0 = kt * 64;
    // ---- stage K/V tile via DMA (swizzled) ----
#pragma unroll
    for (int j = 0; j < 4; ++j) {
      const int slot = j * 256 + tid;
      {
        const int rowl = slot >> 4, cp = slot & 15, cps = cp ^ (rowl & 7);
        load_lds16(kb + (size_t)(k0 + rowl) * HD + cps * 8, &Ks[slot * 8]);
      }
      {
        const int rowd = slot >> 3, cp = slot & 7, cps = cp ^ (rowd & 7);
        load_lds16(vb + (size_t)rowd * S_ + k0 + cps * 8, &Vs[slot * 8]);
      }
    }
    __syncthreads();
    if (k0 <= base + 31) {  // wave has unmasked work in this tile
      // ---- QK^T ----
      f32x4 sc[2][4];
#pragma unroll
      for (int rt = 0; rt < 2; ++rt)
#pragma unroll
        for (int nt = 0; nt < 4; ++nt) sc[rt][nt] = f32x4{0.f, 0.f, 0.f, 0.f};
#pragma unroll
      for (int nt = 0; nt < 4; ++nt) {
#pragma unroll
        for (int c = 0; c < 4; ++c) {
          const bf16x8 kf = *(const bf16x8*)&Ks[(nt * 16 + L15) * 128 + koff[c]];
#pragma unroll
          for (int rt = 0; rt < 2; ++rt)
            sc[rt][nt] = __builtin_amdgcn_mfma_f32_16x16x32_bf16(qf[rt][c], kf, sc[rt][nt], 0, 0, 0);
        }
      }
      if (k0 + 63 > base) {  // diagonal-overlap tile: elementwise causal mask
#pragma unroll
        for (int rt = 0; rt < 2; ++rt)
#pragma unroll
          for (int nt = 0; nt < 4; ++nt) {
            const int col = k0 + nt * 16 + L15;
#pragma unroll
            for (int r = 0; r < 4; ++r) {
              const int row = base + rt * 16 + Lq * 4 + r;
              if (col > row) sc[rt][nt][r] = -1e30f;
            }
          }
      }
      // ---- online softmax ----
#pragma unroll
      for (int rt = 0; rt < 2; ++rt) {
        float mloc[4];
#pragma unroll
        for (int r = 0; r < 4; ++r) {
          mloc[r] = fmaxf(fmaxf(sc[rt][0][r], sc[rt][1][r]), fmaxf(sc[rt][2][r], sc[rt][3][r]));
          mloc[r] = fmaxf(mloc[r], __shfl_xor(mloc[r], 1));
          mloc[r] = fmaxf(mloc[r], __shfl_xor(mloc[r], 2));
          mloc[r] = fmaxf(mloc[r], __shfl_xor(mloc[r], 4));
          mloc[r] = fmaxf(mloc[r], __shfl_xor(mloc[r], 8));
        }
        float mnew[4], alpha[4], rsum[4];
#pragma unroll
        for (int r = 0; r < 4; ++r) {
          mnew[r] = fmaxf(m_i[rt][r], mloc[r]);
          alpha[r] = __expf(m_i[rt][r] - mnew[r]);
          m_i[rt][r] = mnew[r];
          rsum[r] = 0.f;
        }
#pragma unroll
        for (int nt = 0; nt < 4; ++nt)
#pragma unroll
          for (int r = 0; r < 4; ++r) {
            const float pv = __expf(sc[rt][nt][r] - mnew[r]);
            P[wave][(rt * 16 + Lq * 4 + r) * PST + nt * 16 + L15] = f2bf(pv);
            rsum[r] += pv;
          }
#pragma unroll
        for (int r = 0; r < 4; ++r) {
          rsum[r] += __shfl_xor(rsum[r], 1);
          rsum[r] += __shfl_xor(rsum[r], 2);
          rsum[r] += __shfl_xor(rsum[r], 4);
          rsum[r] += __shfl_xor(rsum[r], 8);
          l_i[rt][r] = l_i[rt][r] * alpha[r] + rsum[r];
        }
#pragma unroll
        for (int dt = 0; dt < 8; ++dt)
#pragma unroll
          for (int r = 0; r < 4; ++r) acc[rt][dt][r] *= alpha[r];
      }
      // ---- PV ----  (per-wave P slice; intra-wave lgkm ordering suffices)
      bf16x8 pa[2][2];
#pragma unroll
      for (int rt = 0; rt < 2; ++rt)
#pragma unroll
        for (int kc = 0; kc < 2; ++kc)
          pa[rt][kc] = *(const bf16x8*)&P[wave][(rt * 16 + L15) * PST + kc * 32 + Lq * 8];
#pragma unroll
      for (int dt = 0; dt < 8; ++dt)
#pragma unroll
        for (int kc = 0; kc < 2; ++kc) {
          const bf16x8 vf = *(const bf16x8*)&Vs[(dt * 16 + L15) * 64 + voff[kc]];
#pragma unroll
          for (int rt = 0; rt < 2; ++rt)
            acc[rt][dt] = __builtin_amdgcn_mfma_f32_16x16x32_bf16(pa[rt][kc], vf, acc[rt][dt], 0, 0, 0);
        }
    }
    __syncthreads();
  }
  // ---- epilogue ----
#pragma unroll
  for (int rt = 0; rt < 2; ++rt) {
    float inv[4];
#pragma unroll
    for (int r = 0; r < 4; ++r) inv[r] = 1.f / l_i[rt][r];
    u16* cp = ctx + ((size_t)b * S_ + base + rt * 16) * (NH * HD) + h * HD;
#pragma unroll
    for (int dt = 0; dt < 8; ++dt)
#pragma unroll
      for (int r = 0; r < 4; ++r)
        cp[(size_t)(Lq * 4 + r) * (NH * HD) + dt * 16 + L15] = f2bf(acc[rt][dt][r] * inv[r]);
  }
}

extern "C" void kernel_launch(void* const* d_in, const int* in_sizes, int n_in,
                              void* d_out, int out_size, void* d_ws, size_t ws_size,
                              hipStream_t stream) {
  const float* x     = (const float*)d_in[0];
  const float* W_in  = (const float*)d_in[1];
  const float* b_in  = (const float*)d_in[2];
  const float* cw    = (const float*)d_in[3];
  const float* cb    = (const float*)d_in[4];
  const float* W_out = (const float*)d_in[5];
  const float* b_out = (const float*)d_in[6];

  char* ws = (char*)d_ws;
  u16* xb   = (u16*)(ws);                    // 16777216 B (dead after gemm1)
  u16* wib  = (u16*)(ws + 16777216);         // 12582912 B
  u16* wob  = (u16*)(ws + 29360128);         //  8388608 B
  u16* qkv  = (u16*)(ws + 37748736);         // 25165824 B
  u16* q_ws = (u16*)(ws + 62914560);         // 16777216 B
  u16* k_ws = (u16*)(ws + 79691776);         //  4194304 B
  u16* vt_ws= (u16*)(ws + 83886080);         //  4194304 B
  float* ctab = (float*)ws;                  // rope tables in dead xb region
  float* stab = (float*)(ws + 524288);
  u16* ctx  = xb;                            // alias: xb dead after gemm1

  const int nx = B_ * S_ * E_ / 4, nwi = QKV_ * E_ / 4, nwo = E_ * NH * HD / 4;
  f2b_conv<<<dim3((nx  + 255) / 256), 256, 0, stream>>>(x,     xb,  nx);
  f2b_conv<<<dim3((nwi + 255) / 256), 256, 0, stream>>>(W_in,  wib, nwi);
  f2b_conv<<<dim3((nwo + 255) / 256), 256, 0, stream>>>(W_out, wob, nwo);

  gemm_bt<1><<<dim3(QKV_ / 128, (B_ * S_) / 128), 256, 0, stream>>>(
      xb, wib, b_in, (void*)qkv, B_ * S_, QKV_, E_);
  rope_tab<<<dim3(S_ * 64 / 256), 256, 0, stream>>>(ctab, stab);
  conv_rope<<<dim3(B_ * S_), 256, 0, stream>>>(qkv, cw, cb, ctab, stab, q_ws, k_ws, vt_ws);
  attn<<<dim3(S_ / 128, B_ * NH), 256, 0, stream>>>(q_ws, k_ws, vt_ws, ctx);
  gemm_bt<0><<<dim3(E_ / 128, (B_ * S_) / 128), 256, 0, stream>>>(
      ctx, wob, b_out, d_out, B_ * S_, E_, NH * HD);
}

// Round 5
// 421.595 us; speedup vs baseline: 1.2536x; 1.2536x over previous
//
#include <hip/hip_runtime.h>

#define B_   2
#define S_   2048
#define E_   2048
#define QKV_ 3072
#define NH   16
#define NKV  4
#define HD   128

typedef __attribute__((ext_vector_type(8))) short bf16x8;
typedef __attribute__((ext_vector_type(4))) float f32x4;
typedef unsigned short u16;
typedef unsigned int   u32;

__device__ __forceinline__ float bf2f(u16 u) {
  union { u32 i; float f; } v; v.i = ((u32)u) << 16; return v.f;
}
__device__ __forceinline__ u16 f2bf(float f) {
  union { float f; u32 u; } v; v.f = f;
  return (u16)((v.u + 0x7FFFu + ((v.u >> 16) & 1u)) >> 16);
}
__device__ __forceinline__ void load_lds16(const u16* g, u16* l) {
  __builtin_amdgcn_global_load_lds((const __attribute__((address_space(1))) void*)g,
                                   (__attribute__((address_space(3))) void*)l, 16, 0, 0);
}

// ---------------- fp32 -> bf16 bulk convert (n multiple of 4) ----------------
__global__ __launch_bounds__(256) void f2b_conv(const float* __restrict__ in,
                                                u16* __restrict__ out, int n4) {
  const int i = blockIdx.x * 256 + threadIdx.x;
  if (i >= n4) return;
  const float4 v = ((const float4*)in)[i];
  ushort4 o;
  o.x = f2bf(v.x); o.y = f2bf(v.y); o.z = f2bf(v.z); o.w = f2bf(v.w);
  ((ushort4*)out)[i] = o;
}

// ---------------- rope table: cos/sin[s*64+i] ----------------
__global__ __launch_bounds__(256) void rope_tab(float* __restrict__ c,
                                                float* __restrict__ s) {
  const int idx = blockIdx.x * 256 + threadIdx.x;  // 2048*64
  const int t = idx >> 6, i = idx & 63;
  const float invf = powf(10000.0f, -(float)i * (1.0f / 64.0f));
  float sn, cs;
  sincosf((float)t * invf, &sn, &cs);
  c[idx] = cs; s[idx] = sn;
}

// ---------------- GEMM: C[M,N] = A[M,K] * B[N,K]^T + bias[N] ----------------
template <int OUT_BF16>
__global__ __launch_bounds__(256) void gemm_bt(const u16* __restrict__ A,
                                               const u16* __restrict__ Bm,
                                               const float* __restrict__ bias,
                                               void* __restrict__ C,
                                               int M, int N, int K) {
  __shared__ u16 As[128 * 32];
  __shared__ u16 Bs[128 * 32];
  const int tid = threadIdx.x;
  const int wave = tid >> 6, lane = tid & 63;
  const int m0 = blockIdx.y * 128, n0 = blockIdx.x * 128;
  const int wm = (wave & 1) * 64, wn = (wave >> 1) * 64;
  const int L15 = lane & 15, Lq = lane >> 4;
  const int lrow = lane >> 2, lcol = (lane & 3) * 8;

  f32x4 acc[4][4] = {};

  for (int k0 = 0; k0 < K; k0 += 32) {
#pragma unroll
    for (int c = 0; c < 2; ++c) {
      const int chunk = c * 4 + wave;
      const int row = chunk * 16 + lrow;
      load_lds16(A  + (size_t)(m0 + row) * K + k0 + lcol, &As[chunk * 512 + lane * 8]);
      load_lds16(Bm + (size_t)(n0 + row) * K + k0 + lcol, &Bs[chunk * 512 + lane * 8]);
    }
    __syncthreads();
    bf16x8 af[4], bfr[4];
#pragma unroll
    for (int t = 0; t < 4; ++t) {
      af[t]  = *(const bf16x8*)&As[(wm + t * 16 + L15) * 32 + Lq * 8];
      bfr[t] = *(const bf16x8*)&Bs[(wn + t * 16 + L15) * 32 + Lq * 8];
    }
#pragma unroll
    for (int mt = 0; mt < 4; ++mt)
#pragma unroll
      for (int nt = 0; nt < 4; ++nt)
        acc[mt][nt] = __builtin_amdgcn_mfma_f32_16x16x32_bf16(af[mt], bfr[nt], acc[mt][nt], 0, 0, 0);
    __syncthreads();
  }

#pragma unroll
  for (int nt = 0; nt < 4; ++nt) {
    const int col = n0 + wn + nt * 16 + L15;
    const float bv = bias[col];
#pragma unroll
    for (int mt = 0; mt < 4; ++mt) {
#pragma unroll
      for (int r = 0; r < 4; ++r) {
        const int row = m0 + wm + mt * 16 + Lq * 4 + r;
        const float v = acc[mt][nt][r] + bv;
        if (OUT_BF16) ((u16*)C)[(size_t)row * N + col] = f2bf(v);
        else          ((float*)C)[(size_t)row * N + col] = v;
      }
    }
  }
}

// ------------- depthwise causal conv(4) + bias + RoPE + split/layout -------------
__global__ __launch_bounds__(256) void conv_rope(const u16* __restrict__ qkv,
                                                 const float* __restrict__ cw,
                                                 const float* __restrict__ cb,
                                                 const float* __restrict__ ct,
                                                 const float* __restrict__ st,
                                                 u16* __restrict__ qo,
                                                 u16* __restrict__ ko,
                                                 u16* __restrict__ vo) {
  const int bs = blockIdx.x;
  const int b = bs >> 11, s = bs & 2047;
  const int tid = threadIdx.x;

  auto conv2 = [&](int f, float& a0, float& a1) {
    a0 = cb[f]; a1 = cb[f + 1];
    const float4 w0 = *(const float4*)&cw[f * 4];
    const float4 w1 = *(const float4*)&cw[(f + 1) * 4];
    const float wa0[4] = {w0.x, w0.y, w0.z, w0.w};
    const float wa1[4] = {w1.x, w1.y, w1.z, w1.w};
#pragma unroll
    for (int d = 0; d < 4; ++d) {
      const int t = s - 3 + d;
      if (t >= 0) {
        const u32 pk = *(const u32*)&qkv[((size_t)b * S_ + t) * QKV_ + f];
        a0 += wa0[d] * bf2f((u16)pk);
        a1 += wa1[d] * bf2f((u16)(pk >> 16));
      }
    }
  };

  for (int p = tid; p < (NH + NKV) * 32; p += 256) {
    int f1, i; u16* outp; float scale;
    if (p < NH * 32) {
      const int h = p >> 5; i = (p & 31) * 2;
      f1 = h * HD + i;
      outp = qo + ((size_t)(b * NH + h) * S_ + s) * HD;
      scale = 0.08838834764831845f;  // 1/sqrt(128)
    } else {
      const int pk = p - NH * 32;
      const int h = pk >> 5; i = (pk & 31) * 2;
      f1 = NH * HD + h * HD + i;
      outp = ko + ((size_t)(b * NKV + h) * S_ + s) * HD;
      scale = 1.0f;
    }
    float x1a, x1b, x2a, x2b;
    conv2(f1, x1a, x1b);
    conv2(f1 + 64, x2a, x2b);
    const float2 cs = *(const float2*)&ct[s * 64 + i];
    const float2 sn = *(const float2*)&st[s * 64 + i];
    u32 lo = (u32)f2bf((x1a * cs.x - x2a * sn.x) * scale) |
             ((u32)f2bf((x1b * cs.y - x2b * sn.y) * scale) << 16);
    u32 hi = (u32)f2bf((x2a * cs.x + x1a * sn.x) * scale) |
             ((u32)f2bf((x2b * cs.y + x1b * sn.y) * scale) << 16);
    *(u32*)&outp[i] = lo;
    *(u32*)&outp[i + 64] = hi;
  }
  {
    const int p = tid;
    const int h = p >> 6, d = (p & 63) * 2;
    const int f = (NH + NKV) * HD + h * HD + d;
    float v0, v1;
    conv2(f, v0, v1);
    u16* vp = vo + ((size_t)(b * NKV + h) * HD + d) * S_ + s;
    vp[0]  = f2bf(v0);
    vp[S_] = f2bf(v1);
  }
}

// ------------------------- flash attention (causal, GQA) -------------------------
// grid (8, B*NH); block i handles q-tiles qt=i and qt=15-i (128 rows each) ->
// 34 k-tile iterations per block, perfectly balanced, 256 blocks = 1/CU.
// K/V tiles double-buffered: DMA for kt+1 issued before computing kt.
#define PST 72
__global__ __launch_bounds__(256, 1) void attn(const u16* __restrict__ q,
                                               const u16* __restrict__ k,
                                               const u16* __restrict__ v,
                                               u16* __restrict__ ctx) {
  __shared__ u16 Ks[2][64 * 128];
  __shared__ u16 Vs[2][128 * 64];
  __shared__ u16 P[4][32 * PST];
  const int tid = threadIdx.x, wave = tid >> 6, lane = tid & 63;
  const int L15 = lane & 15, Lq = lane >> 4;
  const int bh = blockIdx.y;
  const int b = bh >> 4, h = bh & 15, hk = h >> 2;

  const u16* kb = k + (size_t)(b * NKV + hk) * S_ * HD;
  const u16* vb = v + (size_t)(b * NKV + hk) * HD * S_;

  const int rx = L15 & 7;
  int koff[4], voff[2];
#pragma unroll
  for (int c = 0; c < 4; ++c) koff[c] = ((c * 4 + Lq) ^ rx) * 8;
#pragma unroll
  for (int kc = 0; kc < 2; ++kc) voff[kc] = ((kc * 4 + Lq) ^ rx) * 8;

  // staging decomposition (wave-uniform LDS base + lane*16B per DMA)
  const int ksl = tid >> 4, kcp = tid & 15;           // K: 16 rows/j, 16 chunks
  const int vsl = tid >> 3, vcp = tid & 7;            // V: 32 rows/j, 8 chunks

  for (int pass = 0; pass < 2; ++pass) {
    const int qt = pass ? (15 - blockIdx.x) : blockIdx.x;
    const int q0 = qt * 128;
    const int base = q0 + wave * 32;

    bf16x8 qf[2][4];
#pragma unroll
    for (int rt = 0; rt < 2; ++rt) {
      const u16* qp = q + ((size_t)bh * S_ + base + rt * 16 + L15) * HD + Lq * 8;
#pragma unroll
      for (int c = 0; c < 4; ++c) qf[rt][c] = *(const bf16x8*)(qp + c * 32);
    }

    f32x4 acc[2][8] = {};
    float m_i[2][4], l_i[2][4];
#pragma unroll
    for (int rt = 0; rt < 2; ++rt)
#pragma unroll
      for (int r = 0; r < 4; ++r) { m_i[rt][r] = -1e30f; l_i[rt][r] = 0.f; }

    const int ktmax = 2 * (qt + 1);

    // stage tile 0 -> buf 0
#pragma unroll
    for (int j = 0; j < 4; ++j) {
      const int krow = j * 16 + ksl;
      load_lds16(kb + (size_t)krow * HD + (kcp ^ (krow & 7)) * 8,
                 &Ks[0][(krow * 16 + kcp) * 8]);
      const int vrow = j * 32 + vsl;
      load_lds16(vb + (size_t)vrow * S_ + (vcp ^ (vrow & 7)) * 8,
                 &Vs[0][(vrow * 8 + vcp) * 8]);
    }
    __syncthreads();

    for (int kt = 0; kt < ktmax; ++kt) {
      const int k0 = kt * 64;
      const int cur = kt & 1;
      if (kt + 1 < ktmax) {  // prefetch next tile into other buffer (DMA in flight)
        const int kn = k0 + 64;
#pragma unroll
        for (int j = 0; j < 4; ++j) {
          const int krow = j * 16 + ksl;
          load_lds16(kb + (size_t)(kn + krow) * HD + (kcp ^ (krow & 7)) * 8,
                     &Ks[cur ^ 1][(krow * 16 + kcp) * 8]);
          const int vrow = j * 32 + vsl;
          load_lds16(vb + (size_t)vrow * S_ + kn + (vcp ^ (vrow & 7)) * 8,
                     &Vs[cur ^ 1][(vrow * 8 + vcp) * 8]);
        }
      }
      if (k0 <= base + 31) {  // wave has unmasked work in this tile
        // ---- QK^T ----
        f32x4 sc[2][4];
#pragma unroll
        for (int rt = 0; rt < 2; ++rt)
#pragma unroll
          for (int nt = 0; nt < 4; ++nt) sc[rt][nt] = f32x4{0.f, 0.f, 0.f, 0.f};
#pragma unroll
        for (int nt = 0; nt < 4; ++nt) {
#pragma unroll
          for (int c = 0; c < 4; ++c) {
            const bf16x8 kf = *(const bf16x8*)&Ks[cur][(nt * 16 + L15) * 128 + koff[c]];
#pragma unroll
            for (int rt = 0; rt < 2; ++rt)
              sc[rt][nt] = __builtin_amdgcn_mfma_f32_16x16x32_bf16(qf[rt][c], kf, sc[rt][nt], 0, 0, 0);
          }
        }
        if (k0 + 63 > base) {  // diagonal-overlap tile
#pragma unroll
          for (int rt = 0; rt < 2; ++rt)
#pragma unroll
            for (int nt = 0; nt < 4; ++nt) {
              const int col = k0 + nt * 16 + L15;
#pragma unroll
              for (int r = 0; r < 4; ++r) {
                const int row = base + rt * 16 + Lq * 4 + r;
                if (col > row) sc[rt][nt][r] = -1e30f;
              }
            }
        }
        // ---- online softmax ----
#pragma unroll
        for (int rt = 0; rt < 2; ++rt) {
          float mloc[4];
#pragma unroll
          for (int r = 0; r < 4; ++r) {
            mloc[r] = fmaxf(fmaxf(sc[rt][0][r], sc[rt][1][r]), fmaxf(sc[rt][2][r], sc[rt][3][r]));
            mloc[r] = fmaxf(mloc[r], __shfl_xor(mloc[r], 1));
            mloc[r] = fmaxf(mloc[r], __shfl_xor(mloc[r], 2));
            mloc[r] = fmaxf(mloc[r], __shfl_xor(mloc[r], 4));
            mloc[r] = fmaxf(mloc[r], __shfl_xor(mloc[r], 8));
          }
          float mnew[4], alpha[4], rsum[4];
#pragma unroll
          for (int r = 0; r < 4; ++r) {
            mnew[r] = fmaxf(m_i[rt][r], mloc[r]);
            alpha[r] = __expf(m_i[rt][r] - mnew[r]);
            m_i[rt][r] = mnew[r];
            rsum[r] = 0.f;
          }
#pragma unroll
          for (int nt = 0; nt < 4; ++nt)
#pragma unroll
            for (int r = 0; r < 4; ++r) {
              const float pv = __expf(sc[rt][nt][r] - mnew[r]);
              P[wave][(rt * 16 + Lq * 4 + r) * PST + nt * 16 + L15] = f2bf(pv);
              rsum[r] += pv;
            }
#pragma unroll
          for (int r = 0; r < 4; ++r) {
            rsum[r] += __shfl_xor(rsum[r], 1);
            rsum[r] += __shfl_xor(rsum[r], 2);
            rsum[r] += __shfl_xor(rsum[r], 4);
            rsum[r] += __shfl_xor(rsum[r], 8);
            l_i[rt][r] = l_i[rt][r] * alpha[r] + rsum[r];
          }
#pragma unroll
          for (int dt = 0; dt < 8; ++dt)
#pragma unroll
            for (int r = 0; r < 4; ++r) acc[rt][dt][r] *= alpha[r];
        }
        // ---- PV ----
        bf16x8 pa[2][2];
#pragma unroll
        for (int rt = 0; rt < 2; ++rt)
#pragma unroll
          for (int kc = 0; kc < 2; ++kc)
            pa[rt][kc] = *(const bf16x8*)&P[wave][(rt * 16 + L15) * PST + kc * 32 + Lq * 8];
#pragma unroll
        for (int dt = 0; dt < 8; ++dt)
#pragma unroll
          for (int kc = 0; kc < 2; ++kc) {
            const bf16x8 vf = *(const bf16x8*)&Vs[cur][(dt * 16 + L15) * 64 + voff[kc]];
#pragma unroll
            for (int rt = 0; rt < 2; ++rt)
              acc[rt][dt] = __builtin_amdgcn_mfma_f32_16x16x32_bf16(pa[rt][kc], vf, acc[rt][dt], 0, 0, 0);
          }
      }
      __syncthreads();  // readers of buf[cur] done + DMA into buf[cur^1] drained
    }
    // ---- epilogue ----
#pragma unroll
    for (int rt = 0; rt < 2; ++rt) {
      float inv[4];
#pragma unroll
      for (int r = 0; r < 4; ++r) inv[r] = 1.f / l_i[rt][r];
      u16* cp = ctx + ((size_t)b * S_ + base + rt * 16) * (NH * HD) + h * HD;
#pragma unroll
      for (int dt = 0; dt < 8; ++dt)
#pragma unroll
        for (int r = 0; r < 4; ++r)
          cp[(size_t)(Lq * 4 + r) * (NH * HD) + dt * 16 + L15] = f2bf(acc[rt][dt][r] * inv[r]);
    }
  }
}

extern "C" void kernel_launch(void* const* d_in, const int* in_sizes, int n_in,
                              void* d_out, int out_size, void* d_ws, size_t ws_size,
                              hipStream_t stream) {
  const float* x     = (const float*)d_in[0];
  const float* W_in  = (const float*)d_in[1];
  const float* b_in  = (const float*)d_in[2];
  const float* cw    = (const float*)d_in[3];
  const float* cb    = (const float*)d_in[4];
  const float* W_out = (const float*)d_in[5];
  const float* b_out = (const float*)d_in[6];

  char* ws = (char*)d_ws;
  u16* xb   = (u16*)(ws);                    // 16777216 B (dead after gemm1)
  u16* wib  = (u16*)(ws + 16777216);         // 12582912 B
  u16* wob  = (u16*)(ws + 29360128);         //  8388608 B
  u16* qkv  = (u16*)(ws + 37748736);         // 25165824 B
  u16* q_ws = (u16*)(ws + 62914560);         // 16777216 B
  u16* k_ws = (u16*)(ws + 79691776);         //  4194304 B
  u16* vt_ws= (u16*)(ws + 83886080);         //  4194304 B
  float* ctab = (float*)ws;                  // rope tables in dead xb region
  float* stab = (float*)(ws + 524288);
  u16* ctx  = xb;                            // alias: xb dead after gemm1

  const int nx = B_ * S_ * E_ / 4, nwi = QKV_ * E_ / 4, nwo = E_ * NH * HD / 4;
  f2b_conv<<<dim3((nx  + 255) / 256), 256, 0, stream>>>(x,     xb,  nx);
  f2b_conv<<<dim3((nwi + 255) / 256), 256, 0, stream>>>(W_in,  wib, nwi);
  f2b_conv<<<dim3((nwo + 255) / 256), 256, 0, stream>>>(W_out, wob, nwo);

  gemm_bt<1><<<dim3(QKV_ / 128, (B_ * S_) / 128), 256, 0, stream>>>(
      xb, wib, b_in, (void*)qkv, B_ * S_, QKV_, E_);
  rope_tab<<<dim3(S_ * 64 / 256), 256, 0, stream>>>(ctab, stab);
  conv_rope<<<dim3(B_ * S_), 256, 0, stream>>>(qkv, cw, cb, ctab, stab, q_ws, k_ws, vt_ws);
  attn<<<dim3(8, B_ * NH), 256, 0, stream>>>(q_ws, k_ws, vt_ws, ctx);
  gemm_bt<0><<<dim3(E_ / 128, (B_ * S_) / 128), 256, 0, stream>>>(
      ctx, wob, b_out, d_out, B_ * S_, E_, NH * HD);
}